// Round 7
// baseline (502.141 us; speedup 1.0000x reference)
//
#include <hip/hip_runtime.h>
#include <hip/hip_bf16.h>

// ConcatModel (all I/O f32; internal MFMA compute bf16, f32 accumulate):
// embed-gather(cvt) -> input-proj GEMM writing xp in MFMA-FRAGMENT layout ->
// ONE persistent LSTM recurrence kernel (W_hh in AGPRs, c in VGPRs, xp read
// direct to regs, L3-coherent h exchange, atomic-return barrier fast path)
// -> feat -> (BN -> GEMM+ReLU) x2 -> BN -> tiny output GEMM.

typedef __attribute__((ext_vector_type(8))) short bf16x8;
typedef __attribute__((ext_vector_type(4))) float f32x4;
typedef __attribute__((ext_vector_type(4))) unsigned int u32x4;

#define DEVI __device__ __forceinline__

template<int N> struct IC { static constexpr int v = N; };

DEVI void async16(const void* g, void* l) {
  __builtin_amdgcn_global_load_lds((const __attribute__((address_space(1))) void*)g,
                                   (__attribute__((address_space(3))) void*)l,
                                   16, 0, 0);
}
// device-coherent (sc0|sc1): bypass stale L1/L2, read at the coherence point
DEVI void async16_coh(const void* g, void* l) {
  __builtin_amdgcn_global_load_lds((const __attribute__((address_space(1))) void*)g,
                                   (__attribute__((address_space(3))) void*)l,
                                   16, 0, 17);
}
// device-coherent 16B store (visible to all XCDs once vmcnt retires)
DEVI void store16_coh(void* addr, u32x4 v) {
  asm volatile("global_store_dwordx4 %0, %1, off sc0 sc1" ::"v"(addr), "v"(v) : "memory");
}
DEVI bf16x8 load16_pin(const void* addr) {  // issue-order-pinned 16B load to VGPRs
  bf16x8 r;
  asm volatile("global_load_dwordx4 %0, %1, off" : "=v"(r) : "v"(addr) : "memory");
  return r;
}
template<int N> DEVI void vmwait_barrier() {
  asm volatile("s_waitcnt vmcnt(%0)" ::"i"(N) : "memory");
  __builtin_amdgcn_s_barrier();
  __builtin_amdgcn_sched_barrier(0);
}
DEVI float sigmf_(float x) { return 1.f / (1.f + __expf(-x)); }
DEVI float tanhf_(float x) {
  float a = __expf(-2.f * fabsf(x));
  float t = (1.f - a) / (1.f + a);
  return copysignf(t, x);
}
DEVI __hip_bfloat16 f2b(float x) { return __float2bfloat16(x); }
DEVI float b2f(__hip_bfloat16 x) { return __bfloat162float(x); }

// ---------------------------------------------------------------------------
__global__ void cvt_f32_bf16(const float* __restrict__ src,
                             __hip_bfloat16* __restrict__ dst, int n4) {
  int i = blockIdx.x * 256 + threadIdx.x;
  int stride = gridDim.x * 256;
  for (; i < n4; i += stride) {
    float4 v = ((const float4*)src)[i];
    union { __hip_bfloat16 h[4]; uint2 u; } o;
    o.h[0] = f2b(v.x); o.h[1] = f2b(v.y); o.h[2] = f2b(v.z); o.h[3] = f2b(v.w);
    ((uint2*)dst)[i] = o.u;
  }
}

__global__ void pack_wih(const float* __restrict__ W_ih,
                         const float* __restrict__ b_ih,
                         const float* __restrict__ b_hh,
                         __hip_bfloat16* __restrict__ WihP,
                         float* __restrict__ biasL) {
  int tid = blockIdx.x * 256 + threadIdx.x;
  int stride = gridDim.x * 256;
  for (int i = tid; i < 2048 * 320; i += stride) {
    int r = i / 320, c = i - r * 320;
    WihP[i] = (c < 300) ? f2b(W_ih[r * 300 + c]) : f2b(0.f);
  }
  if (tid < 2048) biasL[tid] = b_ih[tid] + b_hh[tid];
}

// gather+cvt: Ain[m][0..319] bf16, m = t*512 + n; n<256 premise else hypothesis.
__global__ void gather_kernel(const int* __restrict__ prem, const int* __restrict__ hyp,
                              const float* __restrict__ embed,
                              __hip_bfloat16* __restrict__ Ain) {
  int row = blockIdx.x * 4 + (threadIdx.x >> 6);
  int lane = threadIdx.x & 63;
  int tt = row >> 9, n = row & 511;
  int tok = (n < 256) ? prem[tt * 256 + n] : hyp[tt * 256 + (n - 256)];
  const float4* e4 = (const float4*)(embed + (size_t)tok * 300);  // 75 x 16B
  uint2* d2 = (uint2*)(Ain + (size_t)row * 320);                  // 80 x 8B
  for (int j = lane; j < 75; j += 64) {
    float4 v = e4[j];
    union { __hip_bfloat16 h[4]; uint2 u; } o;
    o.h[0] = f2b(v.x); o.h[1] = f2b(v.y); o.h[2] = f2b(v.z); o.h[3] = f2b(v.w);
    d2[j] = o.u;
  }
  for (int j = 75 + lane; j < 80; j += 64) d2[j] = make_uint2(0u, 0u);
}

// ---------------------------------------------------------------------------
// Pipelined GEMM: C = A[M][K] * Bn[N][K]^T. BMx128 tile, BK=64, 4 waves 2x2.
// EPI=1: f32 out + bias + relu (row-major, LDS-bounce epilogue).
// EPI=2: bf16 out in MFMA-FRAGMENT layout (no bias): per (wid,i,j) quad,
//        addr = slot*512 + lane*8, slot = ((bx*16+by)*4+wid)*16 + i*4+j.
template<int BM, int EPI>
__global__ __launch_bounds__(256)
void gemm_pipe(const __hip_bfloat16* __restrict__ A,
               const __hip_bfloat16* __restrict__ Bn,
               const float* __restrict__ bias,
               void* __restrict__ Cout, int K, int ldc) {
  constexpr int BK = 64;
  constexpr int ABYT = BM * BK * 2;
  constexpr int BBYT = 128 * BK * 2;
  constexpr int APW = BM / 32;
  constexpr int IFL = APW + 4;
  constexpr int WM = BM / 2, MT = WM / 16;
  __shared__ alignas(16) char smem[2 * ABYT + 2 * BBYT];

  const int tid = threadIdx.x, lane = tid & 63, wid = tid >> 6;
  const int wrow = wid >> 1, wcol = wid & 1;
  const int m0 = blockIdx.x * BM, n0 = blockIdx.y * 128;
  const int l8 = lane & 7, ld8 = lane >> 3;
  const int swz = (l8 ^ ld8) * 8;

  const __hip_bfloat16* Abase = A + (size_t)m0 * K;
  const __hip_bfloat16* Bbase = Bn + (size_t)n0 * K;

  f32x4 acc[MT][4];
#pragma unroll
  for (int i = 0; i < MT; ++i)
#pragma unroll
    for (int j = 0; j < 4; ++j) acc[i][j] = {0.f, 0.f, 0.f, 0.f};

  auto stage = [&](int buf, int kt) {
    const __hip_bfloat16* as = Abase + kt * BK + swz;
    char* ad = smem + buf * ABYT;
#pragma unroll
    for (int s = 0; s < APW; ++s) {
      int iss = wid * APW + s;
      async16(as + (size_t)(iss * 8 + ld8) * K, ad + iss * 1024);
    }
    const __hip_bfloat16* bs = Bbase + kt * BK + swz;
    char* bd = smem + 2 * ABYT + buf * BBYT;
#pragma unroll
    for (int s = 0; s < 4; ++s) {
      int iss = wid * 4 + s;
      async16(bs + (size_t)(iss * 8 + ld8) * K, bd + iss * 1024);
    }
  };

  const int nk = K / BK;
  stage(0, 0);
  for (int kt = 0; kt < nk; ++kt) {
    if (kt + 1 < nk) {
      stage((kt + 1) & 1, kt + 1);
      vmwait_barrier<IFL>();
    } else {
      vmwait_barrier<0>();
    }
    const __hip_bfloat16* ab = (const __hip_bfloat16*)(smem + (kt & 1) * ABYT);
    const __hip_bfloat16* bb = (const __hip_bfloat16*)(smem + 2 * ABYT + (kt & 1) * BBYT);
#pragma unroll
    for (int kk = 0; kk < BK; kk += 32) {
      bf16x8 af[MT], bf[4];
#pragma unroll
      for (int i = 0; i < MT; ++i) {
        int r = wrow * WM + i * 16 + (lane & 15);
        af[i] = *(const bf16x8*)&ab[r * BK + ((kk + (lane >> 4) * 8) ^ ((r & 7) * 8))];
      }
#pragma unroll
      for (int j = 0; j < 4; ++j) {
        int r = wcol * 64 + j * 16 + (lane & 15);
        bf[j] = *(const bf16x8*)&bb[r * BK + ((kk + (lane >> 4) * 8) ^ ((r & 7) * 8))];
      }
#pragma unroll
      for (int i = 0; i < MT; ++i)
#pragma unroll
        for (int j = 0; j < 4; ++j)
          acc[i][j] = __builtin_amdgcn_mfma_f32_16x16x32_bf16(af[i], bf[j], acc[i][j], 0, 0, 0);
    }
    __builtin_amdgcn_s_barrier();
  }

  if (EPI == 2) {
    // fragment-layout bf16 store: one coalesced 8B store per acc quad
#pragma unroll
    for (int i = 0; i < MT; ++i)
#pragma unroll
      for (int j = 0; j < 4; ++j) {
        union { __hip_bfloat16 h[4]; uint2 u; } o;
#pragma unroll
        for (int rr = 0; rr < 4; ++rr) o.h[rr] = f2b(acc[i][j][rr]);
        size_t slot = (((size_t)blockIdx.x * 16 + blockIdx.y) * 4 + wid) * 16 + i * 4 + j;
        *(uint2*)((char*)Cout + slot * 512 + lane * 8) = o.u;
      }
    return;
  }

  __syncthreads();
  float* Csm = (float*)smem;
#pragma unroll
  for (int i = 0; i < MT; ++i)
#pragma unroll
    for (int j = 0; j < 4; ++j)
#pragma unroll
      for (int rr = 0; rr < 4; ++rr) {
        int row = wrow * WM + i * 16 + (lane >> 4) * 4 + rr;
        int col = wcol * 64 + j * 16 + (lane & 15);
        Csm[row * 128 + (col ^ ((row & 7) << 2))] = acc[i][j][rr];
      }
  __syncthreads();
#pragma unroll
  for (int it = 0; it < BM / 16; ++it) {
    int idx = it * 256 + tid;
    int row = idx >> 4;
    int cb = (idx & 15) * 8;
    int sw = (row & 7) << 2;
    float4 v0 = *(const float4*)&Csm[row * 128 + (cb ^ sw)];
    float4 v1 = *(const float4*)&Csm[row * 128 + ((cb + 4) ^ sw)];
    float4 b0 = *(const float4*)&bias[n0 + cb];
    float4 b1 = *(const float4*)&bias[n0 + cb + 4];
    v0.x = fmaxf(v0.x + b0.x, 0.f); v0.y = fmaxf(v0.y + b0.y, 0.f);
    v0.z = fmaxf(v0.z + b0.z, 0.f); v0.w = fmaxf(v0.w + b0.w, 0.f);
    v1.x = fmaxf(v1.x + b1.x, 0.f); v1.y = fmaxf(v1.y + b1.y, 0.f);
    v1.z = fmaxf(v1.z + b1.z, 0.f); v1.w = fmaxf(v1.w + b1.w, 0.f);
    size_t base = (size_t)(m0 + row) * ldc + n0 + cb;
    *(float4*)&((float*)Cout)[base] = v0;
    *(float4*)&((float*)Cout)[base + 4] = v1;
  }
}

// ---------------------------------------------------------------------------
// Persistent recurrence. 256 wgs co-resident (>80KB LDS forces 1 wg/CU).
// W_hh slice in AGPRs, c in VGPRs, xp read straight to VGPRs (fragment layout),
// h exchange via sc0/sc1 stores + aux=17 loads, atomic-return barrier.
// LDS: [0,64K) A k-tiles (8x8KB); post-loop aliases: gsm f32[64][129] @0,
// hsm bf16[64][40] @40960.
__global__ __launch_bounds__(256, 1)
void lstm_persist(const __hip_bfloat16* __restrict__ xp,
                  const __hip_bfloat16* __restrict__ Whh,
                  const float* __restrict__ biasL,
                  __hip_bfloat16* __restrict__ hA,
                  __hip_bfloat16* __restrict__ hB,
                  int* __restrict__ ctr) {
  extern __shared__ char smem[];
  const int tid = threadIdx.x, lane = tid & 63, wid = tid >> 6;
  const int bid = blockIdx.x;
  const int grp = (bid & 7) | ((bid >> 7) << 3);  // 0..15 (XCD-grouping heuristic)
  const int jt = (bid >> 3) & 15;
  const int m0 = grp * 64;
  const int l8 = lane & 7, ld8 = lane >> 3;
  const int swz = (l8 ^ ld8) * 8;

  // ---- one-time: W slice (128 gate-rows x 512 K) -> 32 B-frags (AGPR file) ----
  bf16x8 w[2][16];
  for (int h = 0; h < 2; ++h) {
#pragma unroll
    for (int kt = 0; kt < 8; ++kt)
#pragma unroll
      for (int s = 0; s < 2; ++s) {
        int iss = wid * 2 + s;
        int r = h * 64 + iss * 8 + ld8;
        int g = jt * 32 + (r >> 5) * 512 + (r & 31);  // gate-chunk i,f,g,o
        async16(Whh + (size_t)g * 512 + kt * 64 + swz,
                smem + kt * 8192 + iss * 1024);
      }
    asm volatile("s_waitcnt vmcnt(0)" ::: "memory");
    __builtin_amdgcn_s_barrier();
    __builtin_amdgcn_sched_barrier(0);
    if ((wid >> 1) == h) {
      const __hip_bfloat16* wb = (const __hip_bfloat16*)smem;
      const int lw = wid & 1;
#pragma unroll
      for (int j = 0; j < 2; ++j)
#pragma unroll
        for (int ka = 0; ka < 16; ++ka) {
          int r = lw * 32 + j * 16 + (lane & 15);
          int kt = ka >> 1, kk = (ka & 1) * 32;
          w[j][ka] = *(const bf16x8*)&wb[kt * 4096 + r * 64 +
                                         ((kk + (lane >> 4) * 8) ^ ((r & 7) * 8))];
        }
    }
    __syncthreads();
  }

  // pointwise/fragment ownership constants
  const int jsel = (lane >> 5) & 1;
  const int qx = (lane >> 3) & 3;            // lane_x>>4
  const int lane_x = (lane & 31) * 2;
  const int lane_lo = (lane & 7) * 2;        // even 0..14
  const int col5b = jsel * 16 + lane_lo;     // base gate-slice col (cc adds 0/1)
  const int wrx = grp & 1;                   // fragment wrow
  const int wcx = (jt & 3) >> 1;             // fragment wcol
  const int widx = wrx * 2 + wcx;
  const int jx = (jt & 1) * 2 + jsel;        // fragment j
  const int ntb = jt >> 2;                   // nt2 = g*4 + ntb

  float bias_[4][2];
#pragma unroll
  for (int g = 0; g < 4; ++g)
#pragma unroll
    for (int cc = 0; cc < 2; ++cc)
      bias_[g][cc] = biasL[g * 512 + jt * 32 + col5b + cc];

  float c_[8];
#pragma unroll
  for (int e = 0; e < 8; ++e) c_[e] = 0.f;

  for (int t = 0; t < 64; ++t) {
    const __hip_bfloat16* hin = (t & 1) ? hB : hA;
    __hip_bfloat16* hout = (t & 1) ? hA : hB;

    // A stage: 16 issues/thread, kt-major (vmcnt order), device-coherent
#pragma unroll
    for (int kt = 0; kt < 8; ++kt)
#pragma unroll
      for (int s = 0; s < 2; ++s) {
        int iss = wid * 2 + s;
        async16_coh(hin + (size_t)(m0 + iss * 8 + ld8) * 512 + kt * 64 + swz,
                    smem + kt * 8192 + iss * 1024);
      }
    __builtin_amdgcn_sched_barrier(0);
    // xp direct to regs (4 newest vm ops; fragment layout, coalesced 16B)
    const int xrow = (grp < 8) ? (t * 512 + m0) : ((63 - t) * 512 + (m0 - 512));
    const int mt2 = xrow >> 7;
    bf16x8 xg_[4];
#pragma unroll
    for (int g = 0; g < 4; ++g) {
      size_t slot = (((size_t)mt2 * 16 + g * 4 + ntb) * 4 + widx) * 16 + wid * 4 + jx;
      xg_[g] = load16_pin((const char*)xp + slot * 512 + lane_x * 8);
    }
    __builtin_amdgcn_sched_barrier(0);

    f32x4 acc[4][2];
#pragma unroll
    for (int i = 0; i < 4; ++i)
#pragma unroll
      for (int j = 0; j < 2; ++j) acc[i][j] = {0.f, 0.f, 0.f, 0.f};

    auto do_kt = [&](auto K) {
      constexpr int KT = decltype(K)::v;
      vmwait_barrier<18 - 2 * KT>();  // A pairs 0..KT retired; xp(4) floats
      const __hip_bfloat16* ab = (const __hip_bfloat16*)(smem + KT * 8192);
#pragma unroll
      for (int kk = 0; kk < 64; kk += 32) {
        bf16x8 af[4];
#pragma unroll
        for (int i = 0; i < 4; ++i) {
          int r = i * 16 + (lane & 15);
          af[i] = *(const bf16x8*)&ab[r * 64 + ((kk + (lane >> 4) * 8) ^ ((r & 7) * 8))];
        }
#pragma unroll
        for (int i = 0; i < 4; ++i)
#pragma unroll
          for (int j = 0; j < 2; ++j)
            acc[i][j] = __builtin_amdgcn_mfma_f32_16x16x32_bf16(
                af[i], w[j][KT * 2 + kk / 32], acc[i][j], 0, 0, 0);
      }
    };
    do_kt(IC<0>{}); do_kt(IC<1>{}); do_kt(IC<2>{}); do_kt(IC<3>{});
    do_kt(IC<4>{}); do_kt(IC<5>{}); do_kt(IC<6>{}); do_kt(IC<7>{});

    __syncthreads();  // A reads done -> gsm/hsm may alias A region
    float* gsm = (float*)smem;                              // [64][129] f32
    __hip_bfloat16* hsm = (__hip_bfloat16*)(smem + 40960);  // [64][40] bf16
#pragma unroll
    for (int i = 0; i < 4; ++i)
#pragma unroll
      for (int j = 0; j < 2; ++j)
#pragma unroll
        for (int rr = 0; rr < 4; ++rr) {
          int row = i * 16 + (lane >> 4) * 4 + rr;
          int col = wid * 32 + j * 16 + (lane & 15);
          gsm[row * 129 + col] = acc[i][j][rr];
        }
    __syncthreads();
    asm volatile("s_waitcnt vmcnt(0)" ::: "memory");  // xg_ regs landed
    __builtin_amdgcn_sched_barrier(0);                // rule #18

    const __hip_bfloat16* x0 = (const __hip_bfloat16*)&xg_[0];
    const __hip_bfloat16* x1 = (const __hip_bfloat16*)&xg_[1];
    const __hip_bfloat16* x2 = (const __hip_bfloat16*)&xg_[2];
    const __hip_bfloat16* x3 = (const __hip_bfloat16*)&xg_[3];
#pragma unroll
    for (int cc = 0; cc < 2; ++cc) {
      int c5 = col5b + cc;
#pragma unroll
      for (int rr = 0; rr < 4; ++rr) {
        int r = wid * 16 + qx * 4 + rr;
        float gi = gsm[r * 129 + c5]      + b2f(x0[cc * 4 + rr]) + bias_[0][cc];
        float gf = gsm[r * 129 + 32 + c5] + b2f(x1[cc * 4 + rr]) + bias_[1][cc];
        float gg = gsm[r * 129 + 64 + c5] + b2f(x2[cc * 4 + rr]) + bias_[2][cc];
        float go = gsm[r * 129 + 96 + c5] + b2f(x3[cc * 4 + rr]) + bias_[3][cc];
        float cn = sigmf_(gf) * c_[cc * 4 + rr] + sigmf_(gi) * tanhf_(gg);
        float hn = sigmf_(go) * tanhf_(cn);
        c_[cc * 4 + rr] = cn;
        hsm[r * 40 + c5] = f2b(hn);
      }
    }
    __syncthreads();
    {  // coalesced 16B device-coherent h store (row-major ownership)
      int pr = tid >> 2, pj = (tid & 3) * 8;
      bf16x8 hv = *(const bf16x8*)&hsm[pr * 40 + pj];
      store16_coh(&hout[(size_t)(m0 + pr) * 512 + jt * 32 + pj], *(const u32x4*)&hv);
    }
    asm volatile("s_waitcnt vmcnt(0)" ::: "memory");  // own store acked
    __syncthreads();                                   // all wg stores acked

    if (t < 63) {
      if (tid == 0) {
        const int target = 16 * (t + 1);
        int got = atomicAdd(&ctr[grp * 64], 1) + 1;  // device-scope arrival
        if (got < target) {                          // last arriver skips polling
          while (__hip_atomic_load(&ctr[grp * 64], __ATOMIC_RELAXED,
                                   __HIP_MEMORY_SCOPE_AGENT) < target)
            __builtin_amdgcn_s_sleep(1);
        }
      }
      __syncthreads();
    }
  }
}

// ---------------------------------------------------------------------------
__global__ void feat_kernel(const __hip_bfloat16* __restrict__ hA, float* __restrict__ feat) {
  int b = blockIdx.x;
  for (int c = threadIdx.x; c < 2048; c += 256) {
    int sec = c >> 9, j = c & 511;
    int row = (sec == 0) ? b : (sec == 1) ? 512 + b : (sec == 2) ? 256 + b : 768 + b;
    feat[b * 2048 + c] = b2f(hA[(size_t)row * 512 + j]);
  }
}

__global__ void bn_stats(const float* __restrict__ x, const float* __restrict__ g,
                         const float* __restrict__ b,
                         float* __restrict__ sc, float* __restrict__ sh) {
  int c = blockIdx.x * 256 + threadIdx.x;
  float s = 0.f, s2 = 0.f;
  for (int r = 0; r < 256; ++r) {
    float v = x[r * 2048 + c];
    s += v;
    s2 += v * v;
  }
  float mu = s * (1.f / 256.f);
  float var = s2 * (1.f / 256.f) - mu * mu;
  float rs = rsqrtf(var + 1e-5f);
  float scale = g[c] * rs;
  sc[c] = scale;
  sh[c] = b[c] - mu * scale;
}

__global__ void bn_apply(const float* __restrict__ x, const float* __restrict__ sc,
                         const float* __restrict__ sh, __hip_bfloat16* __restrict__ xn) {
  int i = blockIdx.x * 256 + threadIdx.x;
  int c = i & 2047;
  xn[i] = f2b(x[i] * sc[c] + sh[c]);
}

__global__ void final_kernel(const float* __restrict__ x2, const float* __restrict__ sc,
                             const float* __restrict__ sh, const float* __restrict__ Wo,
                             const float* __restrict__ bo, float* __restrict__ out) {
  __shared__ float red[3][256];
  int b = blockIdx.x, tid = threadIdx.x;
  float a0 = 0.f, a1 = 0.f, a2 = 0.f;
  for (int c = tid; c < 2048; c += 256) {
    float v = x2[b * 2048 + c] * sc[c] + sh[c];
    a0 += v * Wo[c];
    a1 += v * Wo[2048 + c];
    a2 += v * Wo[4096 + c];
  }
  red[0][tid] = a0; red[1][tid] = a1; red[2][tid] = a2;
  __syncthreads();
  for (int s = 128; s > 0; s >>= 1) {
    if (tid < s) {
      red[0][tid] += red[0][tid + s];
      red[1][tid] += red[1][tid + s];
      red[2][tid] += red[2][tid + s];
    }
    __syncthreads();
  }
  if (tid < 3) out[b * 3 + tid] = red[tid][0] + bo[tid];
}

// ---------------------------------------------------------------------------
extern "C" void kernel_launch(void* const* d_in, const int* in_sizes, int n_in,
                              void* d_out, int out_size, void* d_ws, size_t ws_size,
                              hipStream_t stream) {
  (void)in_sizes; (void)n_in; (void)out_size; (void)ws_size;
  const int* prem = (const int*)d_in[0];
  const int* hyp = (const int*)d_in[1];
  const float* embed = (const float*)d_in[2];
  const float* W_ih = (const float*)d_in[3];
  const float* W_hh = (const float*)d_in[4];
  const float* b_ih = (const float*)d_in[5];
  const float* b_hh = (const float*)d_in[6];
  const float* bn0g = (const float*)d_in[7];
  const float* bn0b = (const float*)d_in[8];
  const float* W0 = (const float*)d_in[9];
  const float* b0 = (const float*)d_in[10];
  const float* bn1g = (const float*)d_in[11];
  const float* bn1b = (const float*)d_in[12];
  const float* W1 = (const float*)d_in[13];
  const float* b1 = (const float*)d_in[14];
  const float* bnog = (const float*)d_in[15];
  const float* bnob = (const float*)d_in[16];
  const float* Wo = (const float*)d_in[17];
  const float* bo = (const float*)d_in[18];
  float* out = (float*)d_out;

  char* w = (char*)d_ws;
  size_t off = 0;
  auto alloc = [&](size_t bytes) {
    void* p = w + off;
    off += (bytes + 255) & ~(size_t)255;
    return p;
  };
  __hip_bfloat16* WihP = (__hip_bfloat16*)alloc((size_t)2048 * 320 * 2);
  __hip_bfloat16* Whhb = (__hip_bfloat16*)alloc((size_t)2048 * 512 * 2);
  __hip_bfloat16* W0b = (__hip_bfloat16*)alloc((size_t)2048 * 2048 * 2);
  __hip_bfloat16* W1b = (__hip_bfloat16*)alloc((size_t)2048 * 2048 * 2);
  float* biasL = (float*)alloc(2048 * 4);
  int* ctr = (int*)alloc(16 * 64 * 4);  // mt-group arrival counters (256B apart)
  __hip_bfloat16* xp = (__hip_bfloat16*)alloc((size_t)32768 * 2048 * 2);  // 128 MiB, fragment layout
  size_t ain_off = off;
  __hip_bfloat16* Ain = (__hip_bfloat16*)alloc((size_t)32768 * 320 * 2);  // 20 MiB
  size_t end_off = off;
  off = ain_off;  // post-GEMM block aliases Ain (dead after xproj)
  __hip_bfloat16* hA = (__hip_bfloat16*)alloc((size_t)1024 * 512 * 2);
  __hip_bfloat16* hB = (__hip_bfloat16*)alloc((size_t)1024 * 512 * 2);
  float* feat = (float*)alloc((size_t)256 * 2048 * 4);
  __hip_bfloat16* xn = (__hip_bfloat16*)alloc((size_t)256 * 2048 * 2);
  float* x1 = (float*)alloc((size_t)256 * 2048 * 4);
  float* x2 = (float*)alloc((size_t)256 * 2048 * 4);
  float* sc0 = (float*)alloc(2048 * 4);
  float* sh0 = (float*)alloc(2048 * 4);
  float* sc1 = (float*)alloc(2048 * 4);
  float* sh1 = (float*)alloc(2048 * 4);
  float* sc2 = (float*)alloc(2048 * 4);
  float* sh2 = (float*)alloc(2048 * 4);
  (void)end_off;

  (void)hipMemsetAsync(ctr, 0, 16 * 64 * 4, stream);  // fresh barrier state EVERY launch
  pack_wih<<<512, 256, 0, stream>>>(W_ih, b_ih, b_hh, WihP, biasL);
  cvt_f32_bf16<<<1024, 256, 0, stream>>>(W_hh, Whhb, 2048 * 512 / 4);
  cvt_f32_bf16<<<2048, 256, 0, stream>>>(W0, W0b, 2048 * 2048 / 4);
  cvt_f32_bf16<<<2048, 256, 0, stream>>>(W1, W1b, 2048 * 2048 / 4);
  gather_kernel<<<8192, 256, 0, stream>>>(prem, hyp, embed, Ain);
  // x_proj (fragment-layout out, bias deferred to lstm): M=32768, N=2048, K=320
  gemm_pipe<128, 2><<<dim3(256, 16), 256, 0, stream>>>(Ain, WihP, biasL, xp, 320, 2048);
  (void)hipMemsetAsync(hA, 0, (size_t)1024 * 512 * 2, stream);  // h0 = 0 (aliases Ain)
  // persistent recurrence: 84KB dyn LDS (>80KB -> exactly 1 wg/CU)
  (void)hipFuncSetAttribute(reinterpret_cast<const void*>(lstm_persist),
                            hipFuncAttributeMaxDynamicSharedMemorySize, 98304);
  lstm_persist<<<256, 256, 86016, stream>>>(xp, Whhb, biasL, hA, hB, ctr);
  feat_kernel<<<256, 256, 0, stream>>>(hA, feat);  // t=63 wrote hA
  bn_stats<<<8, 256, 0, stream>>>(feat, bn0g, bn0b, sc0, sh0);
  bn_apply<<<2048, 256, 0, stream>>>(feat, sc0, sh0, xn);
  gemm_pipe<64, 1><<<dim3(4, 16), 256, 0, stream>>>(xn, W0b, b0, x1, 2048, 2048);
  bn_stats<<<8, 256, 0, stream>>>(x1, bn1g, bn1b, sc1, sh1);
  bn_apply<<<2048, 256, 0, stream>>>(x1, sc1, sh1, xn);
  gemm_pipe<64, 1><<<dim3(4, 16), 256, 0, stream>>>(xn, W1b, b1, x2, 2048, 2048);
  bn_stats<<<8, 256, 0, stream>>>(x2, bnog, bnob, sc2, sh2);
  final_kernel<<<256, 256, 0, stream>>>(x2, sc2, sh2, Wo, bo, out);
}

// Round 8
// 471.631 us; speedup vs baseline: 1.0647x; 1.0647x over previous
//
#include <hip/hip_runtime.h>
#include <hip/hip_bf16.h>

// ConcatModel (all I/O f32; internal MFMA compute bf16, f32 accumulate):
// embed-gather(cvt) -> input-proj GEMM (fragment-layout xp out) -> ONE
// persistent LSTM recurrence (512 wgs = 16 grp x 32 jt2, 2 wg/CU TLP;
// W_hh slice in regs, c in regs, xp direct-to-reg fragment loads, wave-
// aligned conflict-free LDS gate exchange, XCD-vote fast path for h
// exchange through local L2, coherent sc0/sc1 fallback) -> feat ->
// (BN -> GEMM+ReLU) x2 -> BN -> tiny output GEMM.

typedef __attribute__((ext_vector_type(8))) short bf16x8;
typedef __attribute__((ext_vector_type(4))) float f32x4;
typedef __attribute__((ext_vector_type(2))) unsigned int u32x2;

#define DEVI __device__ __forceinline__

template<int N> struct IC { static constexpr int v = N; };

template<int AUX> DEVI void async16t(const void* g, void* l) {
  __builtin_amdgcn_global_load_lds((const __attribute__((address_space(1))) void*)g,
                                   (__attribute__((address_space(3))) void*)l,
                                   16, 0, AUX);
}
DEVI void async16(const void* g, void* l) { async16t<0>(g, l); }
DEVI u32x2 load8_pin(const void* addr) {  // issue-order-pinned 8B load to VGPRs
  u32x2 r;
  asm volatile("global_load_dwordx2 %0, %1, off" : "=v"(r) : "v"(addr) : "memory");
  return r;
}
DEVI void storeh_coh(void* a, unsigned int v) {  // device-coherent 2B store
  asm volatile("global_store_short %0, %1, off sc0 sc1" ::"v"(a), "v"(v) : "memory");
}
template<int N> DEVI void vmwait_barrier() {
  asm volatile("s_waitcnt vmcnt(%0)" ::"i"(N) : "memory");
  __builtin_amdgcn_s_barrier();
  __builtin_amdgcn_sched_barrier(0);
}
DEVI float sigmf_(float x) { return 1.f / (1.f + __expf(-x)); }
DEVI float tanhf_(float x) {
  float a = __expf(-2.f * fabsf(x));
  float t = (1.f - a) / (1.f + a);
  return copysignf(t, x);
}
DEVI __hip_bfloat16 f2b(float x) { return __float2bfloat16(x); }
DEVI float b2f(__hip_bfloat16 x) { return __bfloat162float(x); }

// ---------------------------------------------------------------------------
__global__ void cvt_f32_bf16(const float* __restrict__ src,
                             __hip_bfloat16* __restrict__ dst, int n4) {
  int i = blockIdx.x * 256 + threadIdx.x;
  int stride = gridDim.x * 256;
  for (; i < n4; i += stride) {
    float4 v = ((const float4*)src)[i];
    union { __hip_bfloat16 h[4]; uint2 u; } o;
    o.h[0] = f2b(v.x); o.h[1] = f2b(v.y); o.h[2] = f2b(v.z); o.h[3] = f2b(v.w);
    ((uint2*)dst)[i] = o.u;
  }
}

__global__ void pack_wih(const float* __restrict__ W_ih,
                         const float* __restrict__ b_ih,
                         const float* __restrict__ b_hh,
                         __hip_bfloat16* __restrict__ WihP,
                         float* __restrict__ biasL) {
  int tid = blockIdx.x * 256 + threadIdx.x;
  int stride = gridDim.x * 256;
  for (int i = tid; i < 2048 * 320; i += stride) {
    int r = i / 320, c = i - r * 320;
    WihP[i] = (c < 300) ? f2b(W_ih[r * 300 + c]) : f2b(0.f);
  }
  if (tid < 2048) biasL[tid] = b_ih[tid] + b_hh[tid];
}

__global__ void gather_kernel(const int* __restrict__ prem, const int* __restrict__ hyp,
                              const float* __restrict__ embed,
                              __hip_bfloat16* __restrict__ Ain) {
  int row = blockIdx.x * 4 + (threadIdx.x >> 6);
  int lane = threadIdx.x & 63;
  int tt = row >> 9, n = row & 511;
  int tok = (n < 256) ? prem[tt * 256 + n] : hyp[tt * 256 + (n - 256)];
  const float4* e4 = (const float4*)(embed + (size_t)tok * 300);  // 75 x 16B
  uint2* d2 = (uint2*)(Ain + (size_t)row * 320);                  // 80 x 8B
  for (int j = lane; j < 75; j += 64) {
    float4 v = e4[j];
    union { __hip_bfloat16 h[4]; uint2 u; } o;
    o.h[0] = f2b(v.x); o.h[1] = f2b(v.y); o.h[2] = f2b(v.z); o.h[3] = f2b(v.w);
    d2[j] = o.u;
  }
  for (int j = 75 + lane; j < 80; j += 64) d2[j] = make_uint2(0u, 0u);
}

// ---------------------------------------------------------------------------
// Pipelined GEMM: C = A[M][K] * Bn[N][K]^T. BMx128 tile, BK=64, 4 waves 2x2.
// EPI=1: f32 out + bias + relu (row-major, LDS-bounce epilogue).
// EPI=2: bf16 out in MFMA-FRAGMENT layout (no bias): per (wid,i,j) quad,
//        addr = slot*512 + lane*8, slot = ((bx*16+by)*4+wid)*16 + i*4+j.
template<int BM, int EPI>
__global__ __launch_bounds__(256)
void gemm_pipe(const __hip_bfloat16* __restrict__ A,
               const __hip_bfloat16* __restrict__ Bn,
               const float* __restrict__ bias,
               void* __restrict__ Cout, int K, int ldc) {
  constexpr int BK = 64;
  constexpr int ABYT = BM * BK * 2;
  constexpr int BBYT = 128 * BK * 2;
  constexpr int APW = BM / 32;
  constexpr int IFL = APW + 4;
  constexpr int WM = BM / 2, MT = WM / 16;
  __shared__ alignas(16) char smem[2 * ABYT + 2 * BBYT];

  const int tid = threadIdx.x, lane = tid & 63, wid = tid >> 6;
  const int wrow = wid >> 1, wcol = wid & 1;
  const int m0 = blockIdx.x * BM, n0 = blockIdx.y * 128;
  const int l8 = lane & 7, ld8 = lane >> 3;
  const int swz = (l8 ^ ld8) * 8;

  const __hip_bfloat16* Abase = A + (size_t)m0 * K;
  const __hip_bfloat16* Bbase = Bn + (size_t)n0 * K;

  f32x4 acc[MT][4];
#pragma unroll
  for (int i = 0; i < MT; ++i)
#pragma unroll
    for (int j = 0; j < 4; ++j) acc[i][j] = {0.f, 0.f, 0.f, 0.f};

  auto stage = [&](int buf, int kt) {
    const __hip_bfloat16* as = Abase + kt * BK + swz;
    char* ad = smem + buf * ABYT;
#pragma unroll
    for (int s = 0; s < APW; ++s) {
      int iss = wid * APW + s;
      async16(as + (size_t)(iss * 8 + ld8) * K, ad + iss * 1024);
    }
    const __hip_bfloat16* bs = Bbase + kt * BK + swz;
    char* bd = smem + 2 * ABYT + buf * BBYT;
#pragma unroll
    for (int s = 0; s < 4; ++s) {
      int iss = wid * 4 + s;
      async16(bs + (size_t)(iss * 8 + ld8) * K, bd + iss * 1024);
    }
  };

  const int nk = K / BK;
  stage(0, 0);
  for (int kt = 0; kt < nk; ++kt) {
    if (kt + 1 < nk) {
      stage((kt + 1) & 1, kt + 1);
      vmwait_barrier<IFL>();
    } else {
      vmwait_barrier<0>();
    }
    const __hip_bfloat16* ab = (const __hip_bfloat16*)(smem + (kt & 1) * ABYT);
    const __hip_bfloat16* bb = (const __hip_bfloat16*)(smem + 2 * ABYT + (kt & 1) * BBYT);
#pragma unroll
    for (int kk = 0; kk < BK; kk += 32) {
      bf16x8 af[MT], bf[4];
#pragma unroll
      for (int i = 0; i < MT; ++i) {
        int r = wrow * WM + i * 16 + (lane & 15);
        af[i] = *(const bf16x8*)&ab[r * BK + ((kk + (lane >> 4) * 8) ^ ((r & 7) * 8))];
      }
#pragma unroll
      for (int j = 0; j < 4; ++j) {
        int r = wcol * 64 + j * 16 + (lane & 15);
        bf[j] = *(const bf16x8*)&bb[r * BK + ((kk + (lane >> 4) * 8) ^ ((r & 7) * 8))];
      }
#pragma unroll
      for (int i = 0; i < MT; ++i)
#pragma unroll
        for (int j = 0; j < 4; ++j)
          acc[i][j] = __builtin_amdgcn_mfma_f32_16x16x32_bf16(af[i], bf[j], acc[i][j], 0, 0, 0);
    }
    __builtin_amdgcn_s_barrier();
  }

  if (EPI == 2) {
#pragma unroll
    for (int i = 0; i < MT; ++i)
#pragma unroll
      for (int j = 0; j < 4; ++j) {
        union { __hip_bfloat16 h[4]; uint2 u; } o;
#pragma unroll
        for (int rr = 0; rr < 4; ++rr) o.h[rr] = f2b(acc[i][j][rr]);
        size_t slot = (((size_t)blockIdx.x * 16 + blockIdx.y) * 4 + wid) * 16 + i * 4 + j;
        *(uint2*)((char*)Cout + slot * 512 + lane * 8) = o.u;
      }
    return;
  }

  __syncthreads();
  float* Csm = (float*)smem;
#pragma unroll
  for (int i = 0; i < MT; ++i)
#pragma unroll
    for (int j = 0; j < 4; ++j)
#pragma unroll
      for (int rr = 0; rr < 4; ++rr) {
        int row = wrow * WM + i * 16 + (lane >> 4) * 4 + rr;
        int col = wcol * 64 + j * 16 + (lane & 15);
        Csm[row * 128 + (col ^ ((row & 7) << 2))] = acc[i][j][rr];
      }
  __syncthreads();
#pragma unroll
  for (int it = 0; it < BM / 16; ++it) {
    int idx = it * 256 + tid;
    int row = idx >> 4;
    int cb = (idx & 15) * 8;
    int sw = (row & 7) << 2;
    float4 v0 = *(const float4*)&Csm[row * 128 + (cb ^ sw)];
    float4 v1 = *(const float4*)&Csm[row * 128 + ((cb + 4) ^ sw)];
    float4 b0 = *(const float4*)&bias[n0 + cb];
    float4 b1 = *(const float4*)&bias[n0 + cb + 4];
    v0.x = fmaxf(v0.x + b0.x, 0.f); v0.y = fmaxf(v0.y + b0.y, 0.f);
    v0.z = fmaxf(v0.z + b0.z, 0.f); v0.w = fmaxf(v0.w + b0.w, 0.f);
    v1.x = fmaxf(v1.x + b1.x, 0.f); v1.y = fmaxf(v1.y + b1.y, 0.f);
    v1.z = fmaxf(v1.z + b1.z, 0.f); v1.w = fmaxf(v1.w + b1.w, 0.f);
    size_t base = (size_t)(m0 + row) * ldc + n0 + cb;
    *(float4*)&((float*)Cout)[base] = v0;
    *(float4*)&((float*)Cout)[base + 4] = v1;
  }
}

// ---------------------------------------------------------------------------
// Persistent recurrence, 512 wgs (2/CU): wg = (grp 0..15 = 64 batch rows,
// jt2 0..31 = 16 h-cols -> 64 gate-rows, one gate per wave).
// LDS: [0,32K) A rolling 4x8KB; [32K,48K) gsm 16 planes x 1KB; flag @48K.
__global__ __launch_bounds__(256, 2)
void lstm_persist(const __hip_bfloat16* __restrict__ xp,
                  const __hip_bfloat16* __restrict__ Whh,
                  const float* __restrict__ biasL,
                  __hip_bfloat16* __restrict__ hA,
                  __hip_bfloat16* __restrict__ hB,
                  int* __restrict__ ctr) {
  extern __shared__ char smem[];
  const int tid = threadIdx.x, lane = tid & 63, wid = tid >> 6;
  const int bid = blockIdx.x;
  const int grp = (bid & 7) | ((bid >> 8) << 3);  // 32 members share (bid&7, bid>>8)
  const int jt2 = (bid >> 3) & 31;
  const int m0 = grp * 64;
  const int l8 = lane & 7, ld8 = lane >> 3;
  const int swz = (l8 ^ ld8) * 8;

  // ---- one-time: W slice (64 gate-rows x 512 K) -> 16 B-frags in regs ----
  // wave wid owns gate wid, cols jt2*16..+16 (tile row r = gt*16 + c).
  bf16x8 w[16];
  for (int hh = 0; hh < 2; ++hh) {
#pragma unroll
    for (int kt2 = 0; kt2 < 4; ++kt2)
#pragma unroll
      for (int s = 0; s < 2; ++s) {
        int iss = wid * 2 + s;
        int r = iss * 8 + ld8;                             // tile gate-row 0..63
        int Wrow = (r >> 4) * 512 + jt2 * 16 + (r & 15);   // global W_hh row
        async16(Whh + (size_t)Wrow * 512 + (hh * 4 + kt2) * 64 + swz,
                smem + kt2 * 8192 + iss * 1024);
      }
    asm volatile("s_waitcnt vmcnt(0)" ::: "memory");
    __builtin_amdgcn_s_barrier();
    __builtin_amdgcn_sched_barrier(0);
    {
      const __hip_bfloat16* wb = (const __hip_bfloat16*)smem;
      int r = wid * 16 + (lane & 15);
#pragma unroll
      for (int kt2 = 0; kt2 < 4; ++kt2)
#pragma unroll
        for (int kkh = 0; kkh < 2; ++kkh)
          w[(hh * 4 + kt2) * 2 + kkh] =
              *(const bf16x8*)&wb[kt2 * 4096 + r * 64 +
                                  ((kkh * 32 + (lane >> 4) * 8) ^ ((r & 7) * 8))];
    }
    __syncthreads();
  }

  // ---- one-time: XCD co-location vote (guarded fast path) ----
  int* flag = (int*)(smem + 49152);
  if (tid == 0) {
    int xcd = (int)(__builtin_amdgcn_s_getreg((31 << 11) | 20) & 15);  // HW_REG_XCC_ID
    int o1 = atomicOr(&ctr[grp * 64 + 1], 1 << xcd);
    int o2 = atomicOr(&ctr[1025], 1 << xcd);
    asm volatile("" ::"v"(o1), "v"(o2));  // ORs complete before arrival
    atomicAdd(&ctr[1024], 1);
    while (__hip_atomic_load(&ctr[1024], __ATOMIC_RELAXED, __HIP_MEMORY_SCOPE_AGENT) < 512)
      __builtin_amdgcn_s_sleep(2);
    int gm = __hip_atomic_load(&ctr[grp * 64 + 1], __ATOMIC_RELAXED, __HIP_MEMORY_SCOPE_AGENT);
    int am = __hip_atomic_load(&ctr[1025], __ATOMIC_RELAXED, __HIP_MEMORY_SCOPE_AGENT);
    *flag = (__popc((unsigned)gm) == 1 && __popc((unsigned)am) == 8) ? 1 : 0;
  }
  __syncthreads();
  const bool fastpath = (*flag != 0);
  __syncthreads();

  // per-thread constants
  const int q = lane >> 4, c = lane & 15;           // fragment row-quad / col
  const int widx = (grp & 1) * 2 + ((jt2 & 7) >> 2);  // xproj wave id of our block
  const int jx = jt2 & 3;                             // xproj fragment j
  const int byb = jt2 >> 3;                           // by = g*4 + byb
  float bias_[4];
#pragma unroll
  for (int g = 0; g < 4; ++g) bias_[g] = biasL[g * 512 + jt2 * 16 + c];

  float c_[4];
#pragma unroll
  for (int e = 0; e < 4; ++e) c_[e] = 0.f;

  auto run = [&](auto FC) {
    constexpr bool FAST = decltype(FC)::v;
    constexpr int AUX = FAST ? 1 : 17;  // sc0 (L2-coherent) vs sc0|sc1 (L3)
    for (int t = 0; t < 64; ++t) {
      const __hip_bfloat16* hin = (t & 1) ? hB : hA;
      __hip_bfloat16* hout = (t & 1) ? hA : hB;

      auto issueA = [&](int kt) {
#pragma unroll
        for (int s = 0; s < 2; ++s) {
          int iss = wid * 2 + s;
          async16t<AUX>(hin + (size_t)(m0 + iss * 8 + ld8) * 512 + kt * 64 + swz,
                        smem + (kt & 3) * 8192 + iss * 1024);
        }
      };
      issueA(0); issueA(1); issueA(2);
      __builtin_amdgcn_sched_barrier(0);
      // xp direct to regs: one 8B fragment-quad per gate (wave-contiguous 512B)
      const int xbase = (grp < 8) ? (t * 512 + m0) : ((63 - t) * 512 + (m0 - 512));
      const int bx = xbase >> 7;
      u32x2 xg[4];
#pragma unroll
      for (int g = 0; g < 4; ++g) {
        size_t slot = (((size_t)bx * 16 + g * 4 + byb) * 4 + widx) * 16 + wid * 4 + jx;
        xg[g] = load8_pin((const char*)xp + slot * 512 + lane * 8);
      }
      __builtin_amdgcn_sched_barrier(0);

      f32x4 acc[4];
#pragma unroll
      for (int i = 0; i < 4; ++i) acc[i] = {0.f, 0.f, 0.f, 0.f};

      auto do_kt = [&](auto K) {
        constexpr int KT = decltype(K)::v;
        constexpr int WT[8] = {8, 8, 8, 4, 4, 4, 2, 0};
        vmwait_barrier<WT[KT]>();
        if constexpr (KT < 5) issueA(KT + 3);  // into buf (KT+3)&3, read at KT-1 (done)
        const __hip_bfloat16* ab = (const __hip_bfloat16*)(smem + (KT & 3) * 8192);
#pragma unroll
        for (int kk = 0; kk < 64; kk += 32) {
          bf16x8 af[4];
#pragma unroll
          for (int i = 0; i < 4; ++i) {
            int r = i * 16 + (lane & 15);
            af[i] = *(const bf16x8*)&ab[r * 64 + ((kk + (lane >> 4) * 8) ^ ((r & 7) * 8))];
          }
#pragma unroll
          for (int i = 0; i < 4; ++i)
            acc[i] = __builtin_amdgcn_mfma_f32_16x16x32_bf16(
                af[i], w[KT * 2 + kk / 32], acc[i], 0, 0, 0);
        }
      };
      do_kt(IC<0>{}); do_kt(IC<1>{}); do_kt(IC<2>{}); do_kt(IC<3>{});
      do_kt(IC<4>{}); do_kt(IC<5>{}); do_kt(IC<6>{}); do_kt(IC<7>{});

      // wave-permutation gate exchange: plane (g*4+i), lane*16B (conflict-free)
      float* gsm = (float*)(smem + 32768);
#pragma unroll
      for (int i = 0; i < 4; ++i)
        *(f32x4*)(gsm + (wid * 4 + i) * 256 + lane * 4) = acc[i];
      __syncthreads();
      f32x4 gq[4];
#pragma unroll
      for (int g = 0; g < 4; ++g)
        gq[g] = *(const f32x4*)(gsm + (g * 4 + wid) * 256 + lane * 4);
      asm volatile("s_waitcnt vmcnt(0)" ::: "memory");  // xg regs landed
      __builtin_amdgcn_sched_barrier(0);

      union { u32x2 v; __hip_bfloat16 h[4]; } X[4];
#pragma unroll
      for (int g = 0; g < 4; ++g) X[g].v = xg[g];
      __hip_bfloat16* hbase = hout + (size_t)(m0 + wid * 16 + q * 4) * 512 + jt2 * 16 + c;
#pragma unroll
      for (int rr = 0; rr < 4; ++rr) {
        float gi = gq[0][rr] + b2f(X[0].h[rr]) + bias_[0];
        float gf = gq[1][rr] + b2f(X[1].h[rr]) + bias_[1];
        float gg = gq[2][rr] + b2f(X[2].h[rr]) + bias_[2];
        float go = gq[3][rr] + b2f(X[3].h[rr]) + bias_[3];
        float cn = sigmf_(gf) * c_[rr] + sigmf_(gi) * tanhf_(gg);
        float hn = sigmf_(go) * tanhf_(cn);
        c_[rr] = cn;
        union { __hip_bfloat16 b; unsigned short u; } hb;
        hb.b = f2b(hn);
        if constexpr (FAST) {
          hbase[rr * 512] = hb.b;  // plain store -> local L2 (same-XCD coherent)
        } else {
          storeh_coh(hbase + rr * 512, (unsigned int)hb.u);
        }
      }
      asm volatile("s_waitcnt vmcnt(0)" ::: "memory");  // h stores acked
      __syncthreads();

      if (t < 63) {
        if (tid == 0) {
          const int target = 32 * (t + 1);
          int got = atomicAdd(&ctr[grp * 64], 1) + 1;
          if (got < target) {
            while (__hip_atomic_load(&ctr[grp * 64], __ATOMIC_RELAXED,
                                     __HIP_MEMORY_SCOPE_AGENT) < target)
              __builtin_amdgcn_s_sleep(1);
          }
        }
        __syncthreads();
      }
    }
  };
  if (fastpath) run(IC<1>{});
  else          run(IC<0>{});
}

// ---------------------------------------------------------------------------
__global__ void feat_kernel(const __hip_bfloat16* __restrict__ hA, float* __restrict__ feat) {
  int b = blockIdx.x;
  for (int c = threadIdx.x; c < 2048; c += 256) {
    int sec = c >> 9, j = c & 511;
    int row = (sec == 0) ? b : (sec == 1) ? 512 + b : (sec == 2) ? 256 + b : 768 + b;
    feat[b * 2048 + c] = b2f(hA[(size_t)row * 512 + j]);
  }
}

__global__ void bn_stats(const float* __restrict__ x, const float* __restrict__ g,
                         const float* __restrict__ b,
                         float* __restrict__ sc, float* __restrict__ sh) {
  int c = blockIdx.x * 256 + threadIdx.x;
  float s = 0.f, s2 = 0.f;
  for (int r = 0; r < 256; ++r) {
    float v = x[r * 2048 + c];
    s += v;
    s2 += v * v;
  }
  float mu = s * (1.f / 256.f);
  float var = s2 * (1.f / 256.f) - mu * mu;
  float rs = rsqrtf(var + 1e-5f);
  float scale = g[c] * rs;
  sc[c] = scale;
  sh[c] = b[c] - mu * scale;
}

__global__ void bn_apply(const float* __restrict__ x, const float* __restrict__ sc,
                         const float* __restrict__ sh, __hip_bfloat16* __restrict__ xn) {
  int i = blockIdx.x * 256 + threadIdx.x;
  int c = i & 2047;
  xn[i] = f2b(x[i] * sc[c] + sh[c]);
}

__global__ void final_kernel(const float* __restrict__ x2, const float* __restrict__ sc,
                             const float* __restrict__ sh, const float* __restrict__ Wo,
                             const float* __restrict__ bo, float* __restrict__ out) {
  __shared__ float red[3][256];
  int b = blockIdx.x, tid = threadIdx.x;
  float a0 = 0.f, a1 = 0.f, a2 = 0.f;
  for (int c = tid; c < 2048; c += 256) {
    float v = x2[b * 2048 + c] * sc[c] + sh[c];
    a0 += v * Wo[c];
    a1 += v * Wo[2048 + c];
    a2 += v * Wo[4096 + c];
  }
  red[0][tid] = a0; red[1][tid] = a1; red[2][tid] = a2;
  __syncthreads();
  for (int s = 128; s > 0; s >>= 1) {
    if (tid < s) {
      red[0][tid] += red[0][tid + s];
      red[1][tid] += red[1][tid + s];
      red[2][tid] += red[2][tid + s];
    }
    __syncthreads();
  }
  if (tid < 3) out[b * 3 + tid] = red[tid][0] + bo[tid];
}

// ---------------------------------------------------------------------------
extern "C" void kernel_launch(void* const* d_in, const int* in_sizes, int n_in,
                              void* d_out, int out_size, void* d_ws, size_t ws_size,
                              hipStream_t stream) {
  (void)in_sizes; (void)n_in; (void)out_size; (void)ws_size;
  const int* prem = (const int*)d_in[0];
  const int* hyp = (const int*)d_in[1];
  const float* embed = (const float*)d_in[2];
  const float* W_ih = (const float*)d_in[3];
  const float* W_hh = (const float*)d_in[4];
  const float* b_ih = (const float*)d_in[5];
  const float* b_hh = (const float*)d_in[6];
  const float* bn0g = (const float*)d_in[7];
  const float* bn0b = (const float*)d_in[8];
  const float* W0 = (const float*)d_in[9];
  const float* b0 = (const float*)d_in[10];
  const float* bn1g = (const float*)d_in[11];
  const float* bn1b = (const float*)d_in[12];
  const float* W1 = (const float*)d_in[13];
  const float* b1 = (const float*)d_in[14];
  const float* bnog = (const float*)d_in[15];
  const float* bnob = (const float*)d_in[16];
  const float* Wo = (const float*)d_in[17];
  const float* bo = (const float*)d_in[18];
  float* out = (float*)d_out;

  char* w = (char*)d_ws;
  size_t off = 0;
  auto alloc = [&](size_t bytes) {
    void* p = w + off;
    off += (bytes + 255) & ~(size_t)255;
    return p;
  };
  __hip_bfloat16* WihP = (__hip_bfloat16*)alloc((size_t)2048 * 320 * 2);
  __hip_bfloat16* Whhb = (__hip_bfloat16*)alloc((size_t)2048 * 512 * 2);
  __hip_bfloat16* W0b = (__hip_bfloat16*)alloc((size_t)2048 * 2048 * 2);
  __hip_bfloat16* W1b = (__hip_bfloat16*)alloc((size_t)2048 * 2048 * 2);
  float* biasL = (float*)alloc(2048 * 4);
  int* ctr = (int*)alloc(2048 * 4);  // [grp*64]=step, [grp*64+1]=xcd mask, [1024]=cnt, [1025]=mask
  __hip_bfloat16* xp = (__hip_bfloat16*)alloc((size_t)32768 * 2048 * 2);  // 128 MiB, fragment layout
  size_t ain_off = off;
  __hip_bfloat16* Ain = (__hip_bfloat16*)alloc((size_t)32768 * 320 * 2);  // 20 MiB
  size_t end_off = off;
  off = ain_off;  // post-GEMM block aliases Ain (dead after xproj)
  __hip_bfloat16* hA = (__hip_bfloat16*)alloc((size_t)1024 * 512 * 2);
  __hip_bfloat16* hB = (__hip_bfloat16*)alloc((size_t)1024 * 512 * 2);
  float* feat = (float*)alloc((size_t)256 * 2048 * 4);
  __hip_bfloat16* xn = (__hip_bfloat16*)alloc((size_t)256 * 2048 * 2);
  float* x1 = (float*)alloc((size_t)256 * 2048 * 4);
  float* x2 = (float*)alloc((size_t)256 * 2048 * 4);
  float* sc0 = (float*)alloc(2048 * 4);
  float* sh0 = (float*)alloc(2048 * 4);
  float* sc1 = (float*)alloc(2048 * 4);
  float* sh1 = (float*)alloc(2048 * 4);
  float* sc2 = (float*)alloc(2048 * 4);
  float* sh2 = (float*)alloc(2048 * 4);
  (void)end_off;

  (void)hipMemsetAsync(ctr, 0, 2048 * 4, stream);  // fresh barrier/vote state EVERY launch
  pack_wih<<<512, 256, 0, stream>>>(W_ih, b_ih, b_hh, WihP, biasL);
  cvt_f32_bf16<<<1024, 256, 0, stream>>>(W_hh, Whhb, 2048 * 512 / 4);
  cvt_f32_bf16<<<2048, 256, 0, stream>>>(W0, W0b, 2048 * 2048 / 4);
  cvt_f32_bf16<<<2048, 256, 0, stream>>>(W1, W1b, 2048 * 2048 / 4);
  gather_kernel<<<8192, 256, 0, stream>>>(prem, hyp, embed, Ain);
  // x_proj (fragment-layout out, bias deferred to lstm): M=32768, N=2048, K=320
  gemm_pipe<128, 2><<<dim3(256, 16), 256, 0, stream>>>(Ain, WihP, biasL, xp, 320, 2048);
  (void)hipMemsetAsync(hA, 0, (size_t)1024 * 512 * 2, stream);  // h0 = 0 (aliases Ain)
  // persistent recurrence: 512 wgs, 49.5KB dyn LDS -> 2 wg/CU co-resident
  (void)hipFuncSetAttribute(reinterpret_cast<const void*>(lstm_persist),
                            hipFuncAttributeMaxDynamicSharedMemorySize, 65536);
  lstm_persist<<<512, 256, 49408, stream>>>(xp, Whhb, biasL, hA, hB, ctr);
  feat_kernel<<<256, 256, 0, stream>>>(hA, feat);  // t=63 wrote hA
  bn_stats<<<8, 256, 0, stream>>>(feat, bn0g, bn0b, sc0, sh0);
  bn_apply<<<2048, 256, 0, stream>>>(feat, sc0, sh0, xn);
  gemm_pipe<64, 1><<<dim3(4, 16), 256, 0, stream>>>(xn, W0b, b0, x1, 2048, 2048);
  bn_stats<<<8, 256, 0, stream>>>(x1, bn1g, bn1b, sc1, sh1);
  bn_apply<<<2048, 256, 0, stream>>>(x1, sc1, sh1, xn);
  gemm_pipe<64, 1><<<dim3(4, 16), 256, 0, stream>>>(xn, W1b, b1, x2, 2048, 2048);
  bn_stats<<<8, 256, 0, stream>>>(x2, bnog, bnob, sc2, sh2);
  final_kernel<<<256, 256, 0, stream>>>(x2, sc2, sh2, Wo, bo, out);
}